// Round 6
// baseline (510.409 us; speedup 1.0000x reference)
//
#include <hip/hip_runtime.h>

// VQ forward == nearest-code lookup: h = x@W^T + b;  idx = argmax_v(2 h.c_v - |c_v|^2);
// out = table[idx].  R6: scans rebuilt barrier-free — no LDS staging; each wave MFMAs
// B-fragments loaded directly from L2 (table bf16 = 4MB = one XCD L2). wave = 64 rows
// x 1024 codes, 8-wave block = 8 row-subgroups of one split, grid 256 = 32 rc x 8 sp
// (sp == bid&7 == XCD -> each XCD streams one 512KB slice). Algorithm identical to R5.

typedef float f32x4 __attribute__((ext_vector_type(4)));
typedef short s16x8 __attribute__((ext_vector_type(8)));
typedef short s16x4 __attribute__((ext_vector_type(4)));

#define M_TOTAL 16384
#define KDIM 768
#define DQ 256
#define NV 8192
#define MARGIN 1.5f

// ws layout (bytes)
#define OFF_TBF   0u            // ushort[NV*DQ]       4,194,304
#define OFF_WH    4194304u      // ushort[DQ*KDIM]       393,216
#define OFF_WL    4587520u      // ushort[DQ*KDIM]       393,216
#define OFF_C2    4980736u      // float[NV]              32,768
#define OFF_M     5013504u      // uint[M_TOTAL]          65,536
#define OFF_BEST  5079040u      // u64[M_TOTAL]          131,072
#define WS_NEEDED 5210112u

static __device__ inline unsigned short bf_rne(float f) {
  unsigned u = __float_as_uint(f);
  u += 0x7FFFu + ((u >> 16) & 1u);
  return (unsigned short)(u >> 16);
}
static __device__ inline unsigned short bf_tr(float f) {
  return (unsigned short)(__float_as_uint(f) >> 16);
}
static __device__ inline float bf_up(unsigned short s) {
  return __uint_as_float(((unsigned)s) << 16);
}
static __device__ inline unsigned mono(float f) {
  unsigned u = __float_as_uint(f);
  return (u & 0x80000000u) ? ~u : (u | 0x80000000u);
}
static __device__ inline float demono(unsigned k) {
  unsigned u = (k & 0x80000000u) ? (k ^ 0x80000000u) : ~k;
  return __uint_as_float(u);
}
static __device__ inline f32x4 mfma16(s16x8 a, s16x8 b, f32x4 c) {
  return __builtin_amdgcn_mfma_f32_16x16x32_bf16(a, b, c, 0, 0, 0);
}

// ============================ prep ============================
#define PB_TBF 1024
#define PB_C2  32
#define PB_W   192
#define PB_INIT 64

__global__ __launch_bounds__(256) void prep_kernel(
    const float* __restrict__ Wm, const float* __restrict__ table,
    unsigned char* __restrict__ ws) {
  unsigned short* tbf = (unsigned short*)(ws + OFF_TBF);
  unsigned short* Wh  = (unsigned short*)(ws + OFF_WH);
  unsigned short* Wl  = (unsigned short*)(ws + OFF_WL);
  float* c2 = (float*)(ws + OFF_C2);
  unsigned* Mu = (unsigned*)(ws + OFF_M);
  unsigned long long* best = (unsigned long long*)(ws + OFF_BEST);
  const int b = blockIdx.x, t = threadIdx.x;
  if (b < PB_TBF) {
    size_t e0 = ((size_t)b * 256 + t) * 8;
    float4 f0 = *(const float4*)(table + e0);
    float4 f1 = *(const float4*)(table + e0 + 4);
    s16x8 v;
    v[0]=(short)bf_rne(f0.x); v[1]=(short)bf_rne(f0.y);
    v[2]=(short)bf_rne(f0.z); v[3]=(short)bf_rne(f0.w);
    v[4]=(short)bf_rne(f1.x); v[5]=(short)bf_rne(f1.y);
    v[6]=(short)bf_rne(f1.z); v[7]=(short)bf_rne(f1.w);
    *(s16x8*)(tbf + e0) = v;
  } else if (b < PB_TBF + PB_C2) {
    const int v = (b - PB_TBF) * 256 + t;
    const float4* row = (const float4*)(table + (size_t)v * DQ);
    float s = 0.f;
    for (int q = 0; q < 64; ++q) {
      float4 x = row[q];
      s = fmaf(x.x, x.x, s); s = fmaf(x.y, x.y, s);
      s = fmaf(x.z, x.z, s); s = fmaf(x.w, x.w, s);
    }
    c2[v] = s;
  } else if (b < PB_TBF + PB_C2 + PB_W) {
    size_t i = ((size_t)(b - PB_TBF - PB_C2) * 256 + t) * 4;
    float4 f = *(const float4*)(Wm + i);
    float fv[4] = {f.x, f.y, f.z, f.w};
    s16x4 vh, vl;
#pragma unroll
    for (int q = 0; q < 4; ++q) {
      unsigned short hi = bf_tr(fv[q]);
      vh[q] = (short)hi;
      vl[q] = (short)bf_rne(fv[q] - bf_up(hi));
    }
    *(s16x4*)(Wh + i) = vh;
    *(s16x4*)(Wl + i) = vl;
  } else {
    const int i = (b - PB_TBF - PB_C2 - PB_W) * 256 + t;
    Mu[i] = 0u;            // mono(-inf-ish): any real score beats 0
    best[i] = 0ull;
  }
}

// ============================ K1: h = x@W^T + b (3-term bf16 split MFMA) ============================
// grid 512 = 128 row-tiles x 4 col-tiles; block 256 (4 waves), tile 128 rows x 64 cols.
__global__ __launch_bounds__(256, 3) void h_gemm_kernel(
    const float* __restrict__ x, const float* __restrict__ bias,
    const unsigned char* __restrict__ ws, float* __restrict__ hout) {
  const unsigned short* Whp = (const unsigned short*)(ws + OFF_WH);
  const unsigned short* Wlp = (const unsigned short*)(ws + OFF_WL);
  __shared__ unsigned short xh[128 * 40], xl[128 * 40];   // rows x padded 32-k chunk
  __shared__ unsigned short wh[64 * 40],  wl[64 * 40];
  const int t = threadIdx.x;
  const int lane = t & 63, wid = t >> 6;
  const int g = lane >> 4, lm = lane & 15;
  const int row_tile = blockIdx.x >> 2, col_tile = blockIdx.x & 3;
  const int r_ld = t >> 1, half = t & 1;       // x staging: 128 rows x 2 halves
  const int n_ld = t >> 2, qtr = t & 3;        // W staging: 64 n x 4 quarters

  f32x4 acc[2][4];
#pragma unroll
  for (int i = 0; i < 2; ++i)
#pragma unroll
    for (int j = 0; j < 4; ++j) acc[i][j] = (f32x4)0.f;

  const float* xsrc = x + (size_t)(row_tile * 128 + r_ld) * KDIM + half * 16;
  const unsigned short* whs = Whp + (size_t)(col_tile * 64 + n_ld) * KDIM + qtr * 8;
  const unsigned short* wls = Wlp + (size_t)(col_tile * 64 + n_ld) * KDIM + qtr * 8;

  float4 px[4]; s16x8 pwh, pwl;
#pragma unroll
  for (int q = 0; q < 4; ++q) px[q] = *(const float4*)(xsrc + q * 4);
  pwh = *(const s16x8*)(whs);
  pwl = *(const s16x8*)(wls);

  for (int kc = 0; kc < KDIM / 32; ++kc) {
    __syncthreads();   // prior chunk fully consumed
    {
      float fv[16] = {px[0].x, px[0].y, px[0].z, px[0].w,
                      px[1].x, px[1].y, px[1].z, px[1].w,
                      px[2].x, px[2].y, px[2].z, px[2].w,
                      px[3].x, px[3].y, px[3].z, px[3].w};
      s16x8 vh0, vh1, vl0, vl1;
#pragma unroll
      for (int e = 0; e < 8; ++e) {
        unsigned short hi = bf_tr(fv[e]);
        vh0[e] = (short)hi; vl0[e] = (short)bf_rne(fv[e] - bf_up(hi));
      }
#pragma unroll
      for (int e = 0; e < 8; ++e) {
        unsigned short hi = bf_tr(fv[8 + e]);
        vh1[e] = (short)hi; vl1[e] = (short)bf_rne(fv[8 + e] - bf_up(hi));
      }
      const int xb = r_ld * 40 + half * 16;
      *(s16x8*)&xh[xb] = vh0; *(s16x8*)&xh[xb + 8] = vh1;
      *(s16x8*)&xl[xb] = vl0; *(s16x8*)&xl[xb + 8] = vl1;
      const int wb = n_ld * 40 + qtr * 8;
      *(s16x8*)&wh[wb] = pwh;
      *(s16x8*)&wl[wb] = pwl;
    }
    if (kc + 1 < KDIM / 32) {   // prefetch next chunk (hidden under MFMA)
      const int k0 = (kc + 1) * 32;
#pragma unroll
      for (int q = 0; q < 4; ++q) px[q] = *(const float4*)(xsrc + k0 + q * 4);
      pwh = *(const s16x8*)(whs + k0);
      pwl = *(const s16x8*)(wls + k0);
    }
    __syncthreads();   // staged chunk ready
    s16x8 ah[2], al[2], bh[4], bl[4];
#pragma unroll
    for (int fr = 0; fr < 2; ++fr) {
      const int rb2 = (wid * 32 + fr * 16 + lm) * 40 + g * 8;
      ah[fr] = *(const s16x8*)&xh[rb2];
      al[fr] = *(const s16x8*)&xl[rb2];
    }
#pragma unroll
    for (int fc = 0; fc < 4; ++fc) {
      const int cb = (fc * 16 + lm) * 40 + g * 8;
      bh[fc] = *(const s16x8*)&wh[cb];
      bl[fc] = *(const s16x8*)&wl[cb];
    }
#pragma unroll
    for (int fr = 0; fr < 2; ++fr)
#pragma unroll
      for (int fc = 0; fc < 4; ++fc) {
        acc[fr][fc] = mfma16(ah[fr], bh[fc], acc[fr][fc]);
        acc[fr][fc] = mfma16(ah[fr], bl[fc], acc[fr][fc]);
        acc[fr][fc] = mfma16(al[fr], bh[fc], acc[fr][fc]);
      }
  }
  // epilogue: + bias, store fp32 h
#pragma unroll
  for (int fc = 0; fc < 4; ++fc) {
    const int col_g = col_tile * 64 + fc * 16 + lm;
    const float bv = bias[col_g];
#pragma unroll
    for (int fr = 0; fr < 2; ++fr) {
      const int row_base = row_tile * 128 + wid * 32 + fr * 16 + g * 4;
#pragma unroll
      for (int r = 0; r < 4; ++r)
        hout[(size_t)(row_base + r) * DQ + col_g] = acc[fr][fc][r] + bv;
    }
  }
}

// ============================ K2/K3: barrier-free score scan ============================
// grid 256 = 32 row-chunks x 8 code-splits; block 512 = 8 waves = 8 row-subgroups.
// wave: 64 rows x 1024 codes; A-frags (all K) in regs; B-frags direct from L2 (no LDS,
// no __syncthreads). MODE 2: per-row bf16 max -> Mu. MODE 3: margin + exact fp32 rescore.
template<int MODE>
__global__ __launch_bounds__(512, 2) void scan2_kernel(
    const float* __restrict__ h, const float* __restrict__ table,
    unsigned char* __restrict__ ws) {
  const unsigned short* tbf = (const unsigned short*)(ws + OFF_TBF);
  const float* c2 = (const float*)(ws + OFF_C2);
  unsigned* Mu = (unsigned*)(ws + OFF_M);
  unsigned long long* best = (unsigned long long*)(ws + OFF_BEST);

  const int t = threadIdx.x, lane = t & 63, wid = t >> 6;
  const int g = (lane >> 4) & 3, lm = lane & 15;
  const int rc = blockIdx.x >> 3, sp = blockIdx.x & 7;   // sp == bid%8 == XCD
  const int rbase = rc * 512 + wid * 64;
  const int code0 = sp * 1024;

  // A-frags: 64 rows x K=256, bf16-truncated h (128 VGPR)
  s16x8 ah[4][8];
#pragma unroll
  for (int fr = 0; fr < 4; ++fr) {
    const float* hp = h + (size_t)(rbase + fr * 16 + lm) * DQ + g * 8;
#pragma unroll
    for (int ks = 0; ks < 8; ++ks) {
      float4 a0 = *(const float4*)(hp + ks * 32);
      float4 a1 = *(const float4*)(hp + ks * 32 + 4);
      s16x8 v;
      v[0]=(short)bf_tr(a0.x); v[1]=(short)bf_tr(a0.y);
      v[2]=(short)bf_tr(a0.z); v[3]=(short)bf_tr(a0.w);
      v[4]=(short)bf_tr(a1.x); v[5]=(short)bf_tr(a1.y);
      v[6]=(short)bf_tr(a1.z); v[7]=(short)bf_tr(a1.w);
      ah[fr][ks] = v;
    }
  }

  float rmax[4][4];   // MODE2: running bf16-score max per owned row
  float Mrow[4][4];   // MODE3: final max (threshold base)
#pragma unroll
  for (int fr = 0; fr < 4; ++fr)
#pragma unroll
    for (int r = 0; r < 4; ++r) {
      if (MODE == 2) rmax[fr][r] = -3.4e38f;
      else           Mrow[fr][r] = demono(Mu[rbase + fr * 16 + g * 4 + r]);
    }

  const unsigned short* bbase = tbf + (size_t)(code0 + lm) * DQ + g * 8;

  for (int ti = 0; ti < 16; ++ti) {
    const int cbase = code0 + ti * 64;
    f32x4 acc[4][4];
#pragma unroll
    for (int fr = 0; fr < 4; ++fr)
#pragma unroll
      for (int fc = 0; fc < 4; ++fc) acc[fr][fc] = (f32x4)0.f;

#pragma unroll
    for (int fc = 0; fc < 4; ++fc) {
      s16x8 b[8];
#pragma unroll
      for (int ks = 0; ks < 8; ++ks)
        b[ks] = *(const s16x8*)(bbase + (size_t)(ti * 64 + fc * 16) * DQ + ks * 32);
#pragma unroll
      for (int ks = 0; ks < 8; ++ks) {
        acc[0][fc] = mfma16(ah[0][ks], b[ks], acc[0][fc]);
        acc[1][fc] = mfma16(ah[1][ks], b[ks], acc[1][fc]);
        acc[2][fc] = mfma16(ah[2][ks], b[ks], acc[2][fc]);
        acc[3][fc] = mfma16(ah[3][ks], b[ks], acc[3][fc]);
      }
    }

#pragma unroll
    for (int fc = 0; fc < 4; ++fc) {
      const int code_g = cbase + fc * 16 + lm;
      const float cc = c2[code_g];
#pragma unroll
      for (int fr = 0; fr < 4; ++fr)
#pragma unroll
        for (int r = 0; r < 4; ++r) {
          const float s = fmaf(2.f, acc[fr][fc][r], -cc);
          if (MODE == 2) {
            rmax[fr][r] = fmaxf(rmax[fr][r], s);
          } else {
            if (s >= Mrow[fr][r] - MARGIN) {   // candidate: exact fp32 rescore
              const int row_g = rbase + fr * 16 + g * 4 + r;
              const float4* hp4 = (const float4*)(h + (size_t)row_g * DQ);
              const float4* tp4 = (const float4*)(table + (size_t)code_g * DQ);
              float dot = 0.f;
#pragma unroll 4
              for (int q = 0; q < 64; ++q) {
                float4 a = hp4[q], bb = tp4[q];
                dot = fmaf(a.x, bb.x, dot); dot = fmaf(a.y, bb.y, dot);
                dot = fmaf(a.z, bb.z, dot); dot = fmaf(a.w, bb.w, dot);
              }
              const float sx = fmaf(2.f, dot, -cc);
              const unsigned long long key =
                  ((unsigned long long)mono(sx) << 32) |
                  (unsigned long long)(0xFFFFFFFFu - (unsigned)code_g);
              atomicMax(&best[row_g], key);   // ties -> smaller code wins (np.argmax)
            }
          }
        }
    }
  }

  if (MODE == 2) {
#pragma unroll
    for (int fr = 0; fr < 4; ++fr)
#pragma unroll
      for (int r = 0; r < 4; ++r) {
        float v = rmax[fr][r];
        v = fmaxf(v, __shfl_xor(v, 1));
        v = fmaxf(v, __shfl_xor(v, 2));
        v = fmaxf(v, __shfl_xor(v, 4));
        v = fmaxf(v, __shfl_xor(v, 8));
        if (lm == 0) atomicMax(&Mu[rbase + fr * 16 + g * 4 + r], mono(v));
      }
  }
}

// ============================ K4: gather ============================
__global__ __launch_bounds__(256) void gather_kernel(
    const float* __restrict__ table, const unsigned char* __restrict__ ws,
    float* __restrict__ out) {
  const unsigned long long* best = (const unsigned long long*)(ws + OFF_BEST);
  const int row = blockIdx.x * 64 + (threadIdx.x >> 2);
  const int part = threadIdx.x & 3;
  const unsigned code = 0xFFFFFFFFu - (unsigned)(best[row] & 0xFFFFFFFFull);
  const float4* src = (const float4*)(table + (size_t)code * DQ + part * 64);
  float4* dst = (float4*)(out + (size_t)row * DQ + part * 64);
#pragma unroll
  for (int q = 0; q < 16; ++q) dst[q] = src[q];
}

// ============================ fallback (R1, known-good fp32 path) ============================
#define FB_RPB 64
#define FB_NCH 128
#define FB_LDA_H 260
#define FB_LDA_XS 36
#define FB_LDA_WT 258
#define FB_LDA_BS 36
struct FSP0 { float xs[FB_RPB][FB_LDA_XS]; float wt[32][FB_LDA_WT]; };
struct FSP2 { float bs[2][FB_NCH][FB_LDA_BS]; };
struct FSP3 { float rs[FB_RPB][17]; int ri[FB_RPB][17]; int bidx[FB_RPB]; };
union FSMem { FSP0 p0; FSP2 p2; FSP3 p3; };

__global__ __launch_bounds__(256) void fb_c2_kernel(const float* __restrict__ table,
                                                    float* __restrict__ c2) {
  const int v = blockIdx.x * 256 + threadIdx.x;
  const float4* row = (const float4*)(table + (size_t)v * DQ);
  float s = 0.f;
#pragma unroll 8
  for (int q = 0; q < DQ / 4; ++q) {
    float4 t = row[q];
    s = fmaf(t.x, t.x, s); s = fmaf(t.y, t.y, s);
    s = fmaf(t.z, t.z, s); s = fmaf(t.w, t.w, s);
  }
  c2[v] = s;
}

__global__ __launch_bounds__(256) void fb_main_kernel(
    const float* __restrict__ x, const float* __restrict__ Wm,
    const float* __restrict__ bias, const float* __restrict__ table,
    const float* __restrict__ c2, float* __restrict__ out) {
  __shared__ float hs[FB_RPB][FB_LDA_H];
  __shared__ FSMem sm;
  const int tid = threadIdx.x;
  const int tx = tid & 15, ty = tid >> 4;
  const int rowbase = blockIdx.x * FB_RPB;
  float acc0[4][16];
#pragma unroll
  for (int i = 0; i < 4; ++i)
#pragma unroll
    for (int j = 0; j < 16; ++j) acc0[i][j] = 0.f;
  const int r_ld = tid >> 2, s_ld = tid & 3;
  for (int kc = 0; kc < KDIM / 32; ++kc) {
    const int k0 = kc * 32;
    float4 xa = *(const float4*)(x + (size_t)(rowbase + r_ld) * KDIM + k0 + s_ld * 4);
    float4 xb = *(const float4*)(x + (size_t)(rowbase + r_ld) * KDIM + k0 + (s_ld + 4) * 4);
    float4 wv[8];
#pragma unroll
    for (int q = 0; q < 8; ++q)
      wv[q] = *(const float4*)(Wm + (size_t)tid * KDIM + k0 + q * 4);
    __syncthreads();
    *(float4*)&sm.p0.xs[r_ld][s_ld * 4] = xa;
    *(float4*)&sm.p0.xs[r_ld][(s_ld + 4) * 4] = xb;
#pragma unroll
    for (int q = 0; q < 8; ++q) {
      sm.p0.wt[q * 4 + 0][tid] = wv[q].x;
      sm.p0.wt[q * 4 + 1][tid] = wv[q].y;
      sm.p0.wt[q * 4 + 2][tid] = wv[q].z;
      sm.p0.wt[q * 4 + 3][tid] = wv[q].w;
    }
    __syncthreads();
#pragma unroll 4
    for (int k = 0; k < 32; ++k) {
      float a[4];
#pragma unroll
      for (int i = 0; i < 4; ++i) a[i] = sm.p0.xs[ty * 4 + i][k];
#pragma unroll
      for (int j = 0; j < 16; ++j) {
        float w = sm.p0.wt[k][tx + 16 * j];
#pragma unroll
        for (int i = 0; i < 4; ++i) acc0[i][j] = fmaf(a[i], w, acc0[i][j]);
      }
    }
  }
#pragma unroll
  for (int j = 0; j < 16; ++j) {
    float bj = bias[tx + 16 * j];
#pragma unroll
    for (int i = 0; i < 4; ++i)
      hs[ty * 4 + i][tx + 16 * j] = acc0[i][j] + bj;
  }
  __syncthreads();
  float bestv[4]; int bidx[4];
#pragma unroll
  for (int i = 0; i < 4; ++i) { bestv[i] = -3.4e38f; bidx[i] = 0; }
  const int c_ld = tid >> 1, ks_ld = (tid & 1) * 16;
  float4 breg[4];
  {
    const float* src = table + (size_t)c_ld * DQ + ks_ld;
#pragma unroll
    for (int q = 0; q < 4; ++q) breg[q] = *(const float4*)(src + q * 4);
  }
  float acc[4][8];
  for (int ci = 0; ci < 512; ++ci) {
    const int cur = ci & 1, kc = ci & 7, nc = ci >> 3;
    if (kc == 0) {
#pragma unroll
      for (int i = 0; i < 4; ++i)
#pragma unroll
        for (int j = 0; j < 8; ++j) acc[i][j] = 0.f;
    }
    __syncthreads();
#pragma unroll
    for (int q = 0; q < 4; ++q)
      *(float4*)&sm.p2.bs[cur][c_ld][ks_ld + q * 4] = breg[q];
    if (ci + 1 < 512) {
      const int nc2 = (ci + 1) >> 3, kk = (ci + 1) & 7;
      const float* src = table + (size_t)(nc2 * FB_NCH + c_ld) * DQ + kk * 32 + ks_ld;
#pragma unroll
      for (int q = 0; q < 4; ++q) breg[q] = *(const float4*)(src + q * 4);
    }
    __syncthreads();
#pragma unroll
    for (int k4 = 0; k4 < 8; ++k4) {
      float4 a4[4]; float4 b4[8];
#pragma unroll
      for (int i = 0; i < 4; ++i)
        a4[i] = *(const float4*)&hs[ty * 4 + i][kc * 32 + k4 * 4];
#pragma unroll
      for (int j = 0; j < 8; ++j)
        b4[j] = *(const float4*)&sm.p2.bs[cur][tx + 16 * j][k4 * 4];
#pragma unroll
      for (int i = 0; i < 4; ++i)
#pragma unroll
        for (int j = 0; j < 8; ++j) {
          acc[i][j] = fmaf(a4[i].x, b4[j].x, acc[i][j]);
          acc[i][j] = fmaf(a4[i].y, b4[j].y, acc[i][j]);
          acc[i][j] = fmaf(a4[i].z, b4[j].z, acc[i][j]);
          acc[i][j] = fmaf(a4[i].w, b4[j].w, acc[i][j]);
        }
    }
    if (kc == 7) {
#pragma unroll
      for (int j = 0; j < 8; ++j) {
        const int code = nc * FB_NCH + tx + 16 * j;
        const float cc = c2[code];
#pragma unroll
        for (int i = 0; i < 4; ++i) {
          const float s = fmaf(2.f, acc[i][j], -cc);
          if (s > bestv[i]) { bestv[i] = s; bidx[i] = code; }
        }
      }
    }
  }
  __syncthreads();
#pragma unroll
  for (int i = 0; i < 4; ++i) {
    sm.p3.rs[ty * 4 + i][tx] = bestv[i];
    sm.p3.ri[ty * 4 + i][tx] = bidx[i];
  }
  __syncthreads();
  if (tid < FB_RPB) {
    float bsc = sm.p3.rs[tid][0]; int bix = sm.p3.ri[tid][0];
    for (int tt = 1; tt < 16; ++tt) {
      float s = sm.p3.rs[tid][tt]; int ix = sm.p3.ri[tid][tt];
      if (s > bsc || (s == bsc && ix < bix)) { bsc = s; bix = ix; }
    }
    sm.p3.bidx[tid] = bix;
  }
  __syncthreads();
  {
    const int row = tid >> 2, part = tid & 3;
    const int code = sm.p3.bidx[row];
    const float4* src = (const float4*)(table + (size_t)code * DQ + part * 64);
    float4* dst = (float4*)(out + (size_t)(rowbase + row) * DQ + part * 64);
#pragma unroll
    for (int q = 0; q < 16; ++q) dst[q] = src[q];
  }
}

// ============================ launch ============================
extern "C" void kernel_launch(void* const* d_in, const int* in_sizes, int n_in,
                              void* d_out, int out_size, void* d_ws, size_t ws_size,
                              hipStream_t stream) {
  const float* x     = (const float*)d_in[0];
  const float* Wm    = (const float*)d_in[1];
  const float* bias  = (const float*)d_in[2];
  const float* table = (const float*)d_in[3];
  float* out = (float*)d_out;

  if (ws_size < WS_NEEDED) {   // fallback: known-good fp32 path
    float* c2 = (float*)d_ws;
    fb_c2_kernel<<<NV / 256, 256, 0, stream>>>(table, c2);
    fb_main_kernel<<<M_TOTAL / FB_RPB, 256, 0, stream>>>(x, Wm, bias, table, c2, out);
    return;
  }

  unsigned char* ws = (unsigned char*)d_ws;
  prep_kernel<<<PB_TBF + PB_C2 + PB_W + PB_INIT, 256, 0, stream>>>(Wm, table, ws);
  h_gemm_kernel<<<512, 256, 0, stream>>>(x, bias, ws, out);    // h lives in d_out
  scan2_kernel<2><<<256, 512, 0, stream>>>(out, table, ws);    // per-row bf16 max -> Mu
  scan2_kernel<3><<<256, 512, 0, stream>>>(out, table, ws);    // margin + exact rescore
  gather_kernel<<<M_TOTAL / 64, 256, 0, stream>>>(table, ws, out);
}

// Round 7
// 404.017 us; speedup vs baseline: 1.2633x; 1.2633x over previous
//
#include <hip/hip_runtime.h>

// VQ forward == nearest-code lookup: h = x@W^T + b;  idx = argmax_v(2 h.c_v - |c_v|^2);
// out = table[idx].  R7: scans rebuilt on the m97-proven shape — 4-wave blocks,
// wave = 32 rows (A in regs, 64 VGPR) x 32-code LDS tiles (dbuf, swizzled,
// global_load_lds staged), 3 blocks/CU. Algorithm identical to R5/R6.

typedef float f32x4 __attribute__((ext_vector_type(4)));
typedef short s16x8 __attribute__((ext_vector_type(8)));
typedef short s16x4 __attribute__((ext_vector_type(4)));

#define M_TOTAL 16384
#define KDIM 768
#define DQ 256
#define NV 8192
#define MARGIN 1.5f

// ws layout (bytes)
#define OFF_TBF   0u            // ushort[NV*DQ]       4,194,304
#define OFF_WH    4194304u      // ushort[DQ*KDIM]       393,216
#define OFF_WL    4587520u      // ushort[DQ*KDIM]       393,216
#define OFF_C2    4980736u      // float[NV]              32,768
#define OFF_M     5013504u      // uint[M_TOTAL]          65,536
#define OFF_BEST  5079040u      // u64[M_TOTAL]          131,072
#define WS_NEEDED 5210112u

static __device__ inline unsigned short bf_rne(float f) {
  unsigned u = __float_as_uint(f);
  u += 0x7FFFu + ((u >> 16) & 1u);
  return (unsigned short)(u >> 16);
}
static __device__ inline unsigned short bf_tr(float f) {
  return (unsigned short)(__float_as_uint(f) >> 16);
}
static __device__ inline float bf_up(unsigned short s) {
  return __uint_as_float(((unsigned)s) << 16);
}
static __device__ inline unsigned mono(float f) {
  unsigned u = __float_as_uint(f);
  return (u & 0x80000000u) ? ~u : (u | 0x80000000u);
}
static __device__ inline float demono(unsigned k) {
  unsigned u = (k & 0x80000000u) ? (k ^ 0x80000000u) : ~k;
  return __uint_as_float(u);
}
static __device__ inline f32x4 mfma16(s16x8 a, s16x8 b, f32x4 c) {
  return __builtin_amdgcn_mfma_f32_16x16x32_bf16(a, b, c, 0, 0, 0);
}

// ============================ prep ============================
#define PB_TBF 1024
#define PB_C2  32
#define PB_W   192
#define PB_INIT 64

__global__ __launch_bounds__(256) void prep_kernel(
    const float* __restrict__ Wm, const float* __restrict__ table,
    unsigned char* __restrict__ ws) {
  unsigned short* tbf = (unsigned short*)(ws + OFF_TBF);
  unsigned short* Wh  = (unsigned short*)(ws + OFF_WH);
  unsigned short* Wl  = (unsigned short*)(ws + OFF_WL);
  float* c2 = (float*)(ws + OFF_C2);
  unsigned* Mu = (unsigned*)(ws + OFF_M);
  unsigned long long* best = (unsigned long long*)(ws + OFF_BEST);
  const int b = blockIdx.x, t = threadIdx.x;
  if (b < PB_TBF) {
    size_t e0 = ((size_t)b * 256 + t) * 8;
    float4 f0 = *(const float4*)(table + e0);
    float4 f1 = *(const float4*)(table + e0 + 4);
    s16x8 v;
    v[0]=(short)bf_rne(f0.x); v[1]=(short)bf_rne(f0.y);
    v[2]=(short)bf_rne(f0.z); v[3]=(short)bf_rne(f0.w);
    v[4]=(short)bf_rne(f1.x); v[5]=(short)bf_rne(f1.y);
    v[6]=(short)bf_rne(f1.z); v[7]=(short)bf_rne(f1.w);
    *(s16x8*)(tbf + e0) = v;
  } else if (b < PB_TBF + PB_C2) {
    const int v = (b - PB_TBF) * 256 + t;
    const float4* row = (const float4*)(table + (size_t)v * DQ);
    float s = 0.f;
    for (int q = 0; q < 64; ++q) {
      float4 x = row[q];
      s = fmaf(x.x, x.x, s); s = fmaf(x.y, x.y, s);
      s = fmaf(x.z, x.z, s); s = fmaf(x.w, x.w, s);
    }
    c2[v] = s;
  } else if (b < PB_TBF + PB_C2 + PB_W) {
    size_t i = ((size_t)(b - PB_TBF - PB_C2) * 256 + t) * 4;
    float4 f = *(const float4*)(Wm + i);
    float fv[4] = {f.x, f.y, f.z, f.w};
    s16x4 vh, vl;
#pragma unroll
    for (int q = 0; q < 4; ++q) {
      unsigned short hi = bf_tr(fv[q]);
      vh[q] = (short)hi;
      vl[q] = (short)bf_rne(fv[q] - bf_up(hi));
    }
    *(s16x4*)(Wh + i) = vh;
    *(s16x4*)(Wl + i) = vl;
  } else {
    const int i = (b - PB_TBF - PB_C2 - PB_W) * 256 + t;
    Mu[i] = 0u;            // mono(-inf-ish): any real score beats 0
    best[i] = 0ull;
  }
}

// ============================ K1: h = x@W^T + b (3-term bf16 split MFMA) ============================
// grid 512 = 128 row-tiles x 4 col-tiles; block 256 (4 waves), tile 128 rows x 64 cols.
__global__ __launch_bounds__(256, 3) void h_gemm_kernel(
    const float* __restrict__ x, const float* __restrict__ bias,
    const unsigned char* __restrict__ ws, float* __restrict__ hout) {
  const unsigned short* Whp = (const unsigned short*)(ws + OFF_WH);
  const unsigned short* Wlp = (const unsigned short*)(ws + OFF_WL);
  __shared__ unsigned short xh[128 * 40], xl[128 * 40];   // rows x padded 32-k chunk
  __shared__ unsigned short wh[64 * 40],  wl[64 * 40];
  const int t = threadIdx.x;
  const int lane = t & 63, wid = t >> 6;
  const int g = lane >> 4, lm = lane & 15;
  const int row_tile = blockIdx.x >> 2, col_tile = blockIdx.x & 3;
  const int r_ld = t >> 1, half = t & 1;       // x staging: 128 rows x 2 halves
  const int n_ld = t >> 2, qtr = t & 3;        // W staging: 64 n x 4 quarters

  f32x4 acc[2][4];
#pragma unroll
  for (int i = 0; i < 2; ++i)
#pragma unroll
    for (int j = 0; j < 4; ++j) acc[i][j] = (f32x4)0.f;

  const float* xsrc = x + (size_t)(row_tile * 128 + r_ld) * KDIM + half * 16;
  const unsigned short* whs = Whp + (size_t)(col_tile * 64 + n_ld) * KDIM + qtr * 8;
  const unsigned short* wls = Wlp + (size_t)(col_tile * 64 + n_ld) * KDIM + qtr * 8;

  float4 px[4]; s16x8 pwh, pwl;
#pragma unroll
  for (int q = 0; q < 4; ++q) px[q] = *(const float4*)(xsrc + q * 4);
  pwh = *(const s16x8*)(whs);
  pwl = *(const s16x8*)(wls);

  for (int kc = 0; kc < KDIM / 32; ++kc) {
    __syncthreads();   // prior chunk fully consumed
    {
      float fv[16] = {px[0].x, px[0].y, px[0].z, px[0].w,
                      px[1].x, px[1].y, px[1].z, px[1].w,
                      px[2].x, px[2].y, px[2].z, px[2].w,
                      px[3].x, px[3].y, px[3].z, px[3].w};
      s16x8 vh0, vh1, vl0, vl1;
#pragma unroll
      for (int e = 0; e < 8; ++e) {
        unsigned short hi = bf_tr(fv[e]);
        vh0[e] = (short)hi; vl0[e] = (short)bf_rne(fv[e] - bf_up(hi));
      }
#pragma unroll
      for (int e = 0; e < 8; ++e) {
        unsigned short hi = bf_tr(fv[8 + e]);
        vh1[e] = (short)hi; vl1[e] = (short)bf_rne(fv[8 + e] - bf_up(hi));
      }
      const int xb = r_ld * 40 + half * 16;
      *(s16x8*)&xh[xb] = vh0; *(s16x8*)&xh[xb + 8] = vh1;
      *(s16x8*)&xl[xb] = vl0; *(s16x8*)&xl[xb + 8] = vl1;
      const int wb = n_ld * 40 + qtr * 8;
      *(s16x8*)&wh[wb] = pwh;
      *(s16x8*)&wl[wb] = pwl;
    }
    if (kc + 1 < KDIM / 32) {   // prefetch next chunk (hidden under MFMA)
      const int k0 = (kc + 1) * 32;
#pragma unroll
      for (int q = 0; q < 4; ++q) px[q] = *(const float4*)(xsrc + k0 + q * 4);
      pwh = *(const s16x8*)(whs + k0);
      pwl = *(const s16x8*)(wls + k0);
    }
    __syncthreads();   // staged chunk ready
    s16x8 ah[2], al[2], bh[4], bl[4];
#pragma unroll
    for (int fr = 0; fr < 2; ++fr) {
      const int rb2 = (wid * 32 + fr * 16 + lm) * 40 + g * 8;
      ah[fr] = *(const s16x8*)&xh[rb2];
      al[fr] = *(const s16x8*)&xl[rb2];
    }
#pragma unroll
    for (int fc = 0; fc < 4; ++fc) {
      const int cb = (fc * 16 + lm) * 40 + g * 8;
      bh[fc] = *(const s16x8*)&wh[cb];
      bl[fc] = *(const s16x8*)&wl[cb];
    }
#pragma unroll
    for (int fr = 0; fr < 2; ++fr)
#pragma unroll
      for (int fc = 0; fc < 4; ++fc) {
        acc[fr][fc] = mfma16(ah[fr], bh[fc], acc[fr][fc]);
        acc[fr][fc] = mfma16(ah[fr], bl[fc], acc[fr][fc]);
        acc[fr][fc] = mfma16(al[fr], bh[fc], acc[fr][fc]);
      }
  }
  // epilogue: + bias, store fp32 h
#pragma unroll
  for (int fc = 0; fc < 4; ++fc) {
    const int col_g = col_tile * 64 + fc * 16 + lm;
    const float bv = bias[col_g];
#pragma unroll
    for (int fr = 0; fr < 2; ++fr) {
      const int row_base = row_tile * 128 + wid * 32 + fr * 16 + g * 4;
#pragma unroll
      for (int r = 0; r < 4; ++r)
        hout[(size_t)(row_base + r) * DQ + col_g] = acc[fr][fc][r] + bv;
    }
  }
}

// ============================ K2/K3: score scan (m97-shape) ============================
// grid 1024 = 128 row-blocks(128 rows) x 8 splits(1024 codes); block 256 = 4 waves.
// wave = 32 rows, A-frags in regs (64 VGPR); B = 32-code x K256 LDS tile (16KB),
// double-buffered, global_load_lds staged with pre-swizzled source (granule ^= code&7),
// one barrier per tile (T3 minimum pipeline). 3 blocks/CU.
// MODE 2: per-row bf16 max -> Mu.   MODE 3: margin filter + exact fp32 rescore -> best.
template<int MODE>
__global__ __launch_bounds__(256, 3) void scan3_kernel(
    const float* __restrict__ h, const float* __restrict__ table,
    unsigned char* __restrict__ ws) {
  const unsigned short* tbf = (const unsigned short*)(ws + OFF_TBF);
  const float* c2 = (const float*)(ws + OFF_C2);
  unsigned* Mu = (unsigned*)(ws + OFF_M);
  unsigned long long* best = (unsigned long long*)(ws + OFF_BEST);
  __shared__ unsigned short bt[2][32 * 256];   // 2 x 16KB, swizzled (granule ^ code&7)

  const int t = threadIdx.x, lane = t & 63, wid = t >> 6;
  const int g4 = lane >> 4, lm = lane & 15;
  const int rb = blockIdx.x >> 3, sp = blockIdx.x & 7;   // sp == bid%8 == XCD slice
  const int wrow = rb * 128 + wid * 32;
  const int code0 = sp * 1024;

  // A-frags: wave's 32 rows x K=256, bf16-truncated h (64 VGPR)
  s16x8 ah[2][8];
#pragma unroll
  for (int fr = 0; fr < 2; ++fr) {
    const float* hp = h + (size_t)(wrow + fr * 16 + lm) * DQ + g4 * 8;
#pragma unroll
    for (int ks = 0; ks < 8; ++ks) {
      float4 a0 = *(const float4*)(hp + ks * 32);
      float4 a1 = *(const float4*)(hp + ks * 32 + 4);
      s16x8 v;
      v[0]=(short)bf_tr(a0.x); v[1]=(short)bf_tr(a0.y);
      v[2]=(short)bf_tr(a0.z); v[3]=(short)bf_tr(a0.w);
      v[4]=(short)bf_tr(a1.x); v[5]=(short)bf_tr(a1.y);
      v[6]=(short)bf_tr(a1.z); v[7]=(short)bf_tr(a1.w);
      ah[fr][ks] = v;
    }
  }

  float rm[2][4];   // MODE2: running max.  MODE3: global row max (threshold base)
#pragma unroll
  for (int fr = 0; fr < 2; ++fr)
#pragma unroll
    for (int r = 0; r < 4; ++r) {
      if (MODE == 2) rm[fr][r] = -3.4e38f;
      else           rm[fr][r] = demono(Mu[wrow + fr * 16 + g4 * 4 + r]);
    }

  // Staging geometry: per thread 4 x 16B. LDS linear slot o = p*4096 + t*16 bytes
  // holds (code = o>>9, swizzled granule gsw = (o>>4)&31); source granule = gsw^(code&7).
  int psrc[4], pdst[4];
#pragma unroll
  for (int p = 0; p < 4; ++p) {
    const int o = p * 4096 + t * 16;
    const int code = o >> 9, gsw = (o >> 4) & 31;
    const int gsrc = gsw ^ (code & 7);
    psrc[p] = code * 256 + gsrc * 8;    // ushort offset within a 32-code tile
    pdst[p] = p * 2048 + t * 8;         // ushort offset in bt[buf]
  }
  const unsigned short* sbase = tbf + (size_t)code0 * DQ;

#define STAGE(buf, tilev)                                                     \
  {                                                                           \
    const unsigned short* s0 = sbase + (size_t)(tilev) * 8192;                \
    _Pragma("unroll")                                                         \
    for (int p = 0; p < 4; ++p)                                               \
      __builtin_amdgcn_global_load_lds(                                       \
          (const unsigned int*)(s0 + psrc[p]),                                \
          (unsigned int*)&bt[buf][pdst[p]], 16, 0, 0);                        \
  }

  STAGE(0, 0);
  __syncthreads();   // (drains vmcnt) buf0 ready
  int cur = 0;

  for (int tile = 0; tile < 32; ++tile) {
    if (tile + 1 < 32) STAGE(cur ^ 1, tile + 1);   // in flight under compute

    f32x4 acc[2][2];
#pragma unroll
    for (int fr = 0; fr < 2; ++fr)
#pragma unroll
      for (int fc = 0; fc < 2; ++fc) acc[fr][fc] = (f32x4)0.f;

#pragma unroll
    for (int ks = 0; ks < 8; ++ks) {
      const int gb = ks * 4 + g4;
      const int c0 = lm,      gr0 = gb ^ (c0 & 7);
      const int c1 = 16 + lm, gr1 = gb ^ (c1 & 7);
      s16x8 b0 = *(const s16x8*)&bt[cur][c0 * 256 + gr0 * 8];
      s16x8 b1 = *(const s16x8*)&bt[cur][c1 * 256 + gr1 * 8];
      acc[0][0] = mfma16(ah[0][ks], b0, acc[0][0]);
      acc[1][0] = mfma16(ah[1][ks], b0, acc[1][0]);
      acc[0][1] = mfma16(ah[0][ks], b1, acc[0][1]);
      acc[1][1] = mfma16(ah[1][ks], b1, acc[1][1]);
    }

#pragma unroll
    for (int fc = 0; fc < 2; ++fc) {
      const int code_g = code0 + tile * 32 + fc * 16 + lm;
      const float cc = c2[code_g];
#pragma unroll
      for (int fr = 0; fr < 2; ++fr)
#pragma unroll
        for (int r = 0; r < 4; ++r) {
          const float s = fmaf(2.f, acc[fr][fc][r], -cc);
          if (MODE == 2) {
            rm[fr][r] = fmaxf(rm[fr][r], s);
          } else {
            if (s >= rm[fr][r] - MARGIN) {   // candidate: exact fp32 rescore
              const int row_g = wrow + fr * 16 + g4 * 4 + r;
              const float4* hp4 = (const float4*)(h + (size_t)row_g * DQ);
              const float4* tp4 = (const float4*)(table + (size_t)code_g * DQ);
              float dot = 0.f;
#pragma unroll 4
              for (int q = 0; q < 64; ++q) {
                float4 a = hp4[q], bb = tp4[q];
                dot = fmaf(a.x, bb.x, dot); dot = fmaf(a.y, bb.y, dot);
                dot = fmaf(a.z, bb.z, dot); dot = fmaf(a.w, bb.w, dot);
              }
              const float sx = fmaf(2.f, dot, -cc);
              const unsigned long long key =
                  ((unsigned long long)mono(sx) << 32) |
                  (unsigned long long)(0xFFFFFFFFu - (unsigned)code_g);
              atomicMax(&best[row_g], key);   // ties -> smaller code wins (np.argmax)
            }
          }
        }
    }

    __syncthreads();   // drains next-tile stage + guards buffer flip
    cur ^= 1;
  }
#undef STAGE

  if (MODE == 2) {
#pragma unroll
    for (int fr = 0; fr < 2; ++fr)
#pragma unroll
      for (int r = 0; r < 4; ++r) {
        float v = rm[fr][r];
        v = fmaxf(v, __shfl_xor(v, 1));
        v = fmaxf(v, __shfl_xor(v, 2));
        v = fmaxf(v, __shfl_xor(v, 4));
        v = fmaxf(v, __shfl_xor(v, 8));
        if (lm == 0) atomicMax(&Mu[wrow + fr * 16 + g4 * 4 + r], mono(v));
      }
  }
}

// ============================ K4: gather ============================
__global__ __launch_bounds__(256) void gather_kernel(
    const float* __restrict__ table, const unsigned char* __restrict__ ws,
    float* __restrict__ out) {
  const unsigned long long* best = (const unsigned long long*)(ws + OFF_BEST);
  const int row = blockIdx.x * 64 + (threadIdx.x >> 2);
  const int part = threadIdx.x & 3;
  const unsigned code = 0xFFFFFFFFu - (unsigned)(best[row] & 0xFFFFFFFFull);
  const float4* src = (const float4*)(table + (size_t)code * DQ + part * 64);
  float4* dst = (float4*)(out + (size_t)row * DQ + part * 64);
#pragma unroll
  for (int q = 0; q < 16; ++q) dst[q] = src[q];
}

// ============================ fallback (R1, known-good fp32 path) ============================
#define FB_RPB 64
#define FB_NCH 128
#define FB_LDA_H 260
#define FB_LDA_XS 36
#define FB_LDA_WT 258
#define FB_LDA_BS 36
struct FSP0 { float xs[FB_RPB][FB_LDA_XS]; float wt[32][FB_LDA_WT]; };
struct FSP2 { float bs[2][FB_NCH][FB_LDA_BS]; };
struct FSP3 { float rs[FB_RPB][17]; int ri[FB_RPB][17]; int bidx[FB_RPB]; };
union FSMem { FSP0 p0; FSP2 p2; FSP3 p3; };

__global__ __launch_bounds__(256) void fb_c2_kernel(const float* __restrict__ table,
                                                    float* __restrict__ c2) {
  const int v = blockIdx.x * 256 + threadIdx.x;
  const float4* row = (const float4*)(table + (size_t)v * DQ);
  float s = 0.f;
#pragma unroll 8
  for (int q = 0; q < DQ / 4; ++q) {
    float4 t = row[q];
    s = fmaf(t.x, t.x, s); s = fmaf(t.y, t.y, s);
    s = fmaf(t.z, t.z, s); s = fmaf(t.w, t.w, s);
  }
  c2[v] = s;
}

__global__ __launch_bounds__(256) void fb_main_kernel(
    const float* __restrict__ x, const float* __restrict__ Wm,
    const float* __restrict__ bias, const float* __restrict__ table,
    const float* __restrict__ c2, float* __restrict__ out) {
  __shared__ float hs[FB_RPB][FB_LDA_H];
  __shared__ FSMem sm;
  const int tid = threadIdx.x;
  const int tx = tid & 15, ty = tid >> 4;
  const int rowbase = blockIdx.x * FB_RPB;
  float acc0[4][16];
#pragma unroll
  for (int i = 0; i < 4; ++i)
#pragma unroll
    for (int j = 0; j < 16; ++j) acc0[i][j] = 0.f;
  const int r_ld = tid >> 2, s_ld = tid & 3;
  for (int kc = 0; kc < KDIM / 32; ++kc) {
    const int k0 = kc * 32;
    float4 xa = *(const float4*)(x + (size_t)(rowbase + r_ld) * KDIM + k0 + s_ld * 4);
    float4 xb = *(const float4*)(x + (size_t)(rowbase + r_ld) * KDIM + k0 + (s_ld + 4) * 4);
    float4 wv[8];
#pragma unroll
    for (int q = 0; q < 8; ++q)
      wv[q] = *(const float4*)(Wm + (size_t)tid * KDIM + k0 + q * 4);
    __syncthreads();
    *(float4*)&sm.p0.xs[r_ld][s_ld * 4] = xa;
    *(float4*)&sm.p0.xs[r_ld][(s_ld + 4) * 4] = xb;
#pragma unroll
    for (int q = 0; q < 8; ++q) {
      sm.p0.wt[q * 4 + 0][tid] = wv[q].x;
      sm.p0.wt[q * 4 + 1][tid] = wv[q].y;
      sm.p0.wt[q * 4 + 2][tid] = wv[q].z;
      sm.p0.wt[q * 4 + 3][tid] = wv[q].w;
    }
    __syncthreads();
#pragma unroll 4
    for (int k = 0; k < 32; ++k) {
      float a[4];
#pragma unroll
      for (int i = 0; i < 4; ++i) a[i] = sm.p0.xs[ty * 4 + i][k];
#pragma unroll
      for (int j = 0; j < 16; ++j) {
        float w = sm.p0.wt[k][tx + 16 * j];
#pragma unroll
        for (int i = 0; i < 4; ++i) acc0[i][j] = fmaf(a[i], w, acc0[i][j]);
      }
    }
  }
#pragma unroll
  for (int j = 0; j < 16; ++j) {
    float bj = bias[tx + 16 * j];
#pragma unroll
    for (int i = 0; i < 4; ++i)
      hs[ty * 4 + i][tx + 16 * j] = acc0[i][j] + bj;
  }
  __syncthreads();
  float bestv[4]; int bidx[4];
#pragma unroll
  for (int i = 0; i < 4; ++i) { bestv[i] = -3.4e38f; bidx[i] = 0; }
  const int c_ld = tid >> 1, ks_ld = (tid & 1) * 16;
  float4 breg[4];
  {
    const float* src = table + (size_t)c_ld * DQ + ks_ld;
#pragma unroll
    for (int q = 0; q < 4; ++q) breg[q] = *(const float4*)(src + q * 4);
  }
  float acc[4][8];
  for (int ci = 0; ci < 512; ++ci) {
    const int cur = ci & 1, kc = ci & 7, nc = ci >> 3;
    if (kc == 0) {
#pragma unroll
      for (int i = 0; i < 4; ++i)
#pragma unroll
        for (int j = 0; j < 8; ++j) acc[i][j] = 0.f;
    }
    __syncthreads();
#pragma unroll
    for (int q = 0; q < 4; ++q)
      *(float4*)&sm.p2.bs[cur][c_ld][ks_ld + q * 4] = breg[q];
    if (ci + 1 < 512) {
      const int nc2 = (ci + 1) >> 3, kk = (ci + 1) & 7;
      const float* src = table + (size_t)(nc2 * FB_NCH + c_ld) * DQ + kk * 32 + ks_ld;
#pragma unroll
      for (int q = 0; q < 4; ++q) breg[q] = *(const float4*)(src + q * 4);
    }
    __syncthreads();
#pragma unroll
    for (int k4 = 0; k4 < 8; ++k4) {
      float4 a4[4]; float4 b4[8];
#pragma unroll
      for (int i = 0; i < 4; ++i)
        a4[i] = *(const float4*)&hs[ty * 4 + i][kc * 32 + k4 * 4];
#pragma unroll
      for (int j = 0; j < 8; ++j)
        b4[j] = *(const float4*)&sm.p2.bs[cur][tx + 16 * j][k4 * 4];
#pragma unroll
      for (int i = 0; i < 4; ++i)
#pragma unroll
        for (int j = 0; j < 8; ++j) {
          acc[i][j] = fmaf(a4[i].x, b4[j].x, acc[i][j]);
          acc[i][j] = fmaf(a4[i].y, b4[j].y, acc[i][j]);
          acc[i][j] = fmaf(a4[i].z, b4[j].z, acc[i][j]);
          acc[i][j] = fmaf(a4[i].w, b4[j].w, acc[i][j]);
        }
    }
    if (kc == 7) {
#pragma unroll
      for (int j = 0; j < 8; ++j) {
        const int code = nc * FB_NCH + tx + 16 * j;
        const float cc = c2[code];
#pragma unroll
        for (int i = 0; i < 4; ++i) {
          const float s = fmaf(2.f, acc[i][j], -cc);
          if (s > bestv[i]) { bestv[i] = s; bidx[i] = code; }
        }
      }
    }
  }
  __syncthreads();
#pragma unroll
  for (int i = 0; i < 4; ++i) {
    sm.p3.rs[ty * 4 + i][tx] = bestv[i];
    sm.p3.ri[ty * 4 + i][tx] = bidx[i];
  }
  __syncthreads();
  if (tid < FB_RPB) {
    float bsc = sm.p3.rs[tid][0]; int bix = sm.p3.ri[tid][0];
    for (int tt = 1; tt < 16; ++tt) {
      float s = sm.p3.rs[tid][tt]; int ix = sm.p3.ri[tid][tt];
      if (s > bsc || (s == bsc && ix < bix)) { bsc = s; bix = ix; }
    }
    sm.p3.bidx[tid] = bix;
  }
  __syncthreads();
  {
    const int row = tid >> 2, part = tid & 3;
    const int code = sm.p3.bidx[row];
    const float4* src = (const float4*)(table + (size_t)code * DQ + part * 64);
    float4* dst = (float4*)(out + (size_t)(rowbase + row) * DQ + part * 64);
#pragma unroll
    for (int q = 0; q < 16; ++q) dst[q] = src[q];
  }
}

// ============================ launch ============================
extern "C" void kernel_launch(void* const* d_in, const int* in_sizes, int n_in,
                              void* d_out, int out_size, void* d_ws, size_t ws_size,
                              hipStream_t stream) {
  const float* x     = (const float*)d_in[0];
  const float* Wm    = (const float*)d_in[1];
  const float* bias  = (const float*)d_in[2];
  const float* table = (const float*)d_in[3];
  float* out = (float*)d_out;

  if (ws_size < WS_NEEDED) {   // fallback: known-good fp32 path
    float* c2 = (float*)d_ws;
    fb_c2_kernel<<<NV / 256, 256, 0, stream>>>(table, c2);
    fb_main_kernel<<<M_TOTAL / FB_RPB, 256, 0, stream>>>(x, Wm, bias, table, c2, out);
    return;
  }

  unsigned char* ws = (unsigned char*)d_ws;
  prep_kernel<<<PB_TBF + PB_C2 + PB_W + PB_INIT, 256, 0, stream>>>(Wm, table, ws);
  h_gemm_kernel<<<512, 256, 0, stream>>>(x, bias, ws, out);    // h lives in d_out
  scan3_kernel<2><<<1024, 256, 0, stream>>>(out, table, ws);   // per-row bf16 max -> Mu
  scan3_kernel<3><<<1024, 256, 0, stream>>>(out, table, ws);   // margin + exact rescore
  gather_kernel<<<M_TOTAL / 64, 256, 0, stream>>>(table, ws, out);
}